// Round 4
// baseline (1130.005 us; speedup 1.0000x reference)
//
#include <hip/hip_runtime.h>
#include <stdint.h>

// Problem constants
constexpr int BB = 64;     // batch
constexpr int SS = 512;    // seq len
constexpr int DD = 256;    // emb dim
constexpr int HH = 256;    // hidden
constexpr int NHH = 4;     // heads
constexpr int KK = 1024;   // NH*H recurrent input dim

// Recurrence geometry: WG = 512 threads, one WG per batch element.
// Thread t: g = t&63, ch = t>>6. Covers outputs {g, g+64, g+128, g+192}
// over input chunk [128*ch, 128*ch+128) -> 64 uint4 weight slots/thread.
// Slot regions: 52 VGPR (208 regs) + 6 LDS (48 KB) + 6 streamed per step.
// ROUNDS 2-3 LESSON: __launch_bounds__(512,2)'s 2nd arg acted as min
// BLOCKS/CU (CUDA-style) -> 4 waves/EU -> hard 128-VGPR cap -> compiler
// sank all weight loads into the t-loop (re-streamed from L2 every step).
// Fix: amdgpu_waves_per_eu(2,2) pins 2 waves/EU (256-reg budget) and an
// asm pin makes the 52 resident loads non-rematerializable.
constexpr int TT = 512;

typedef _Float16 f16;
typedef _Float16 f16x2 __attribute__((ext_vector_type(2)));

__device__ inline float dot2p(uint32_t a, uint32_t b, float c) {
  f16x2 av = __builtin_bit_cast(f16x2, a);
  f16x2 bv = __builtin_bit_cast(f16x2, b);
#if defined(__has_builtin)
#if __has_builtin(__builtin_amdgcn_fdot2)
  return __builtin_amdgcn_fdot2(av, bv, c, false);
#else
  return c + (float)av.x * (float)bv.x + (float)av.y * (float)bv.y;
#endif
#else
  return c + (float)av.x * (float)bv.x + (float)av.y * (float)bv.y;
#endif
}

__device__ inline float dot8(uint4 w, uint4 a, float c) {
  c = dot2p(w.x, a.x, c);
  c = dot2p(w.y, a.y, c);
  c = dot2p(w.z, a.z, c);
  c = dot2p(w.w, a.w, c);
  return c;
}

__device__ inline uint32_t pack2(float a, float b) {
  f16x2 v;
  v.x = (f16)a;
  v.y = (f16)b;
  return __builtin_bit_cast(uint32_t, v);
}

__device__ inline float fast_tanh(float x) {
  x = fminf(fmaxf(x, -15.f), 15.f);
  float e = __expf(2.f * x);
  return 1.f - 2.f / (e + 1.f);
}

// ---------------------------------------------------------------------------
// Prep A1: pack Wh [256,1024] fp32 -> Wpack f16 in slot layout
// Wpack[m*512 + t], t = ch*64 + g. Slot m -> (j, k):
//   m<52: j=m>>2, k=m&3 | m<56: j=13,k=m-52 | m<60: j=14,k=m-56 | else j=15,k=m-60
// holds Wh[g + 64k][128*ch + 8j .. +8) as 8 packed f16.
// ---------------------------------------------------------------------------
__global__ void k_pack_wh(const float* __restrict__ Wh, uint4* __restrict__ Wpack) {
  int gid = blockIdx.x * blockDim.x + threadIdx.x;  // 32768
  int m = gid >> 9, t = gid & 511;
  int ch = t >> 6, g = t & 63;
  int j, k;
  if (m < 52) {
    j = m >> 2;
    k = m & 3;
  } else if (m < 56) {
    j = 13;
    k = m - 52;
  } else if (m < 60) {
    j = 14;
    k = m - 56;
  } else {
    j = 15;
    k = m - 60;
  }
  int row = g + 64 * k;
  int col = 128 * ch + 8 * j;
  const float* s = Wh + row * KK + col;
  uint4 w;
  w.x = pack2(s[0], s[1]);
  w.y = pack2(s[2], s[3]);
  w.z = pack2(s[4], s[5]);
  w.w = pack2(s[6], s[7]);
  Wpack[gid] = w;
}

// ---------------------------------------------------------------------------
// Prep A2/A3: transpose src[r, C] (r in [0,256)) -> dst[c*256 + r]
// ---------------------------------------------------------------------------
__global__ void k_transpose8(const float* __restrict__ src, float* __restrict__ dst,
                             int C, int total) {
  int gid = blockIdx.x * blockDim.x + threadIdx.x;
  if (gid >= total) return;
  int r = gid & 255, c = gid >> 8;
  dst[gid] = src[r * C + c];
}

// ---------------------------------------------------------------------------
// Prep B: U[row, o] = emb[src[row]] @ Wi^T + bi + bh   (f16 out)
// Column-per-thread (thread = output col o, 32 rows), 8-d tiles.
// ---------------------------------------------------------------------------
__global__ __launch_bounds__(256) void k_precompute_u(
    const int* __restrict__ src, const float* __restrict__ emb,
    const float* __restrict__ WiT, const float* __restrict__ bi,
    const float* __restrict__ bh, f16* __restrict__ U) {
  __shared__ float xs[32 * 256];
  __shared__ int srcs[32];
  const int tid = threadIdx.x;
  const int row0 = blockIdx.x * 32;
  if (tid < 32) srcs[tid] = src[row0 + tid];
  __syncthreads();
  for (int i = tid; i < 32 * 256; i += 256) {
    int r = i >> 8, d = i & 255;
    xs[i] = emb[srcs[r] * DD + d];
  }
  __syncthreads();
  const int o = tid;
  float acc[32];
#pragma unroll
  for (int r = 0; r < 32; ++r) acc[r] = 0.f;
  for (int d0 = 0; d0 < 256; d0 += 8) {
    float w[8];
#pragma unroll
    for (int j = 0; j < 8; ++j) w[j] = WiT[(d0 + j) * 256 + o];  // coalesced
#pragma unroll
    for (int r = 0; r < 32; ++r) {
      const float4* xp = (const float4*)(xs + r * 256 + d0);  // broadcast
      float4 x0 = xp[0], x1 = xp[1];
      acc[r] += x0.x * w[0] + x0.y * w[1] + x0.z * w[2] + x0.w * w[3] +
                x1.x * w[4] + x1.y * w[5] + x1.z * w[6] + x1.w * w[7];
    }
  }
  float bias = bi[o] + bh[o];
#pragma unroll
  for (int r = 0; r < 32; ++r)
    U[(size_t)(row0 + r) * HH + o] = (f16)(acc[r] + bias);
}

// ---------------------------------------------------------------------------
// Main recurrence: one WG (512 threads = 8 waves) per batch element.
// Pinned at exactly 2 waves/EU -> 256-VGPR budget for true weight residency.
// ---------------------------------------------------------------------------
__global__ void __attribute__((amdgpu_flat_work_group_size(512, 512),
                               amdgpu_waves_per_eu(2, 2)))
k_recurrence(
    const uint4* __restrict__ Wpack, const f16* __restrict__ U,
    const float* __restrict__ fix_src, const int* __restrict__ input_len,
    const float* __restrict__ fc1T, const float* __restrict__ fc1_b,
    const float* __restrict__ fc2_W, const float* __restrict__ fc2_b,
    float* __restrict__ out) {
  __shared__ uint4 wlds[6 * TT];      // 48 KB weights (slots 52..57)
  __shared__ uint4 hcatv[KK / 8];     // 2 KB f16 activations
  __shared__ float hstate[NHH * HH];  // 4 KB fp32 master h
  __shared__ float partials[2048];    // 8 KB
  __shared__ float hidb[HH];          // 1 KB  -> total 63 KB
  f16* hcat_h = (f16*)hcatv;

  const int b = blockIdx.x;
  const int t = threadIdx.x;
  const int o = t & 255;
  const int g = t & 63, ch = t >> 6;

  // one-time: weights into VGPRs + LDS
  uint4 wv[52];
#pragma unroll
  for (int m = 0; m < 52; ++m) wv[m] = Wpack[m * TT + t];
  // Pin: consume+produce via opaque asm so the loads above cannot be
  // rematerialized/sunk into the t-loop by the register allocator.
#pragma unroll
  for (int m = 0; m < 52; ++m)
    asm volatile("" : "+v"(wv[m].x), "+v"(wv[m].y), "+v"(wv[m].z), "+v"(wv[m].w));
#pragma unroll
  for (int i = 0; i < 6; ++i) wlds[i * TT + t] = Wpack[(52 + i) * TT + t];
  hstate[t] = 0.f;
  hstate[512 + t] = 0.f;
  if (t < KK / 8) hcatv[t] = make_uint4(0u, 0u, 0u, 0u);
  __syncthreads();

  const uint4* Wstr = Wpack + 58 * TT;  // streamed slots 58..63
  const int len = input_len[b];
  const f16* Ub = U + (size_t)b * SS * HH;
  const float* fsb = fix_src + b * SS;
  const uint4* actp = hcatv + ch * 16;  // wave-uniform base

#pragma unroll 1
  for (int step = 0; step < len; ++step) {
    uint4 st0 = Wstr[t];  // L2 streams issued early; consumed late
    uint4 st1 = Wstr[TT + t];
    uint4 st2 = Wstr[2 * TT + t];
    uint4 st3 = Wstr[3 * TT + t];
    uint4 st4 = Wstr[4 * TT + t];
    uint4 st5 = Wstr[5 * TT + t];
    float uval = 0.f, dval = 0.f;
    if (t < 256) {
      uval = (float)Ub[step * HH + o];
      dval = fsb[step];
    }
    float a0 = 0.f, a1 = 0.f, a2 = 0.f, a3 = 0.f;
#pragma unroll
    for (int j = 0; j < 13; ++j) {
      uint4 a = actp[j];
      a0 = dot8(wv[4 * j + 0], a, a0);
      a1 = dot8(wv[4 * j + 1], a, a1);
      a2 = dot8(wv[4 * j + 2], a, a2);
      a3 = dot8(wv[4 * j + 3], a, a3);
    }
    {
      uint4 a = actp[13];
      a0 = dot8(wlds[0 * TT + t], a, a0);
      a1 = dot8(wlds[1 * TT + t], a, a1);
      a2 = dot8(wlds[2 * TT + t], a, a2);
      a3 = dot8(wlds[3 * TT + t], a, a3);
    }
    {
      uint4 a = actp[14];
      a0 = dot8(wlds[4 * TT + t], a, a0);
      a1 = dot8(wlds[5 * TT + t], a, a1);
      a2 = dot8(st0, a, a2);
      a3 = dot8(st1, a, a3);
    }
    {
      uint4 a = actp[15];
      a0 = dot8(st2, a, a0);
      a1 = dot8(st3, a, a1);
      a2 = dot8(st4, a, a2);
      a3 = dot8(st5, a, a3);
    }
    partials[ch * 256 + g] = a0;
    partials[ch * 256 + 64 + g] = a1;
    partials[ch * 256 + 128 + g] = a2;
    partials[ch * 256 + 192 + g] = a3;
    __syncthreads();
    if (t < 256) {
      float pre = uval;
#pragma unroll
      for (int c2 = 0; c2 < 8; ++c2) pre += partials[c2 * 256 + o];
      float c = fast_tanh(pre);
#pragma unroll
      for (int n = 0; n < NHH; ++n) {
        float gt = 1.f / (1.f + __expf((float)(3 * n) - dval));
        float hn = hstate[n * HH + o];
        hn = gt * c + (1.f - gt) * hn;
        hstate[n * HH + o] = hn;
        hcat_h[n * HH + o] = (f16)hn;
      }
    }
    __syncthreads();
  }

  // ---- epilogue: hid = tanh(sel @ fc1_W^T + fc1_b); out = hid @ fc2_W^T + fc2_b
  {
    float acc = 0.f;
    const int q2 = t >> 8;  // 0..1
    const int base = q2 * 512;
    for (int i = 0; i < 512; ++i) {
      acc += hstate[base + i] * fc1T[(size_t)(base + i) * HH + o];
    }
    partials[q2 * 256 + o] = acc;
  }
  __syncthreads();
  if (t < 256) {
    float pre = partials[o] + partials[256 + o] + fc1_b[o];
    hidb[o] = fast_tanh(pre);
  }
  __syncthreads();
  if (t < 64) {
    float p0 = 0.f, p1 = 0.f;
    for (int oi = t; oi < 256; oi += 64) {
      float h = hidb[oi];
      p0 += h * fc2_W[oi];
      p1 += h * fc2_W[256 + oi];
    }
#pragma unroll
    for (int off = 32; off; off >>= 1) {
      p0 += __shfl_down(p0, off);
      p1 += __shfl_down(p1, off);
    }
    if (t == 0) {
      out[b * 2 + 0] = p0 + fc2_b[0];
      out[b * 2 + 1] = p1 + fc2_b[1];
    }
  }
}

// ---------------------------------------------------------------------------
// Host launcher
// ws layout: [0,512K) Wpack | [512K,768K) WiT | [768K,1792K) fc1T | [1792K,+16M) U
// ---------------------------------------------------------------------------
extern "C" void kernel_launch(void* const* d_in, const int* in_sizes, int n_in,
                              void* d_out, int out_size, void* d_ws, size_t ws_size,
                              hipStream_t stream) {
  const int* src = (const int*)d_in[0];
  const int* input_len = (const int*)d_in[1];
  const float* fix_src = (const float*)d_in[2];
  const float* emb = (const float*)d_in[3];
  const float* Wi = (const float*)d_in[4];
  const float* bi = (const float*)d_in[5];
  const float* Wh = (const float*)d_in[6];
  const float* bh = (const float*)d_in[7];
  const float* fc1_W = (const float*)d_in[8];
  const float* fc1_b = (const float*)d_in[9];
  const float* fc2_W = (const float*)d_in[10];
  const float* fc2_b = (const float*)d_in[11];
  float* out = (float*)d_out;

  char* ws = (char*)d_ws;
  uint4* Wpack = (uint4*)(ws);                 // 512 KB
  float* WiT = (float*)(ws + (512ull << 10));  // 256 KB
  float* fc1T = (float*)(ws + (768ull << 10)); // 1 MB
  f16* U = (f16*)(ws + (1792ull << 10));       // 16 MB
  const size_t needed = (1792ull << 10) + (size_t)BB * SS * HH * sizeof(f16);
  if (ws_size < needed) return;

  k_pack_wh<<<128, 256, 0, stream>>>(Wh, Wpack);
  k_transpose8<<<(65536 + 255) / 256, 256, 0, stream>>>(Wi, WiT, 256, 65536);
  k_transpose8<<<(262144 + 255) / 256, 256, 0, stream>>>(fc1_W, fc1T, 1024, 262144);
  k_precompute_u<<<BB * SS / 32, 256, 0, stream>>>(src, emb, WiT, bi, bh, U);
  k_recurrence<<<BB, TT, 0, stream>>>(Wpack, U, fix_src, input_len, fc1T, fc1_b,
                                      fc2_W, fc2_b, out);
}